// Round 2
// baseline (1153.832 us; speedup 1.0000x reference)
//
#include <hip/hip_runtime.h>

// ---------------- problem constants ----------------
#define NVEC  131072      // 32*4096 vectors
#define DIM   64
#define K     512
#define DECAYF 0.99f
#define OMDF   0.01f
#define EPSF   1e-5f

// ---------------- output layout (floats, concatenated in return order) ----
#define Q_OFF    0
#define DIFF_OFF 8388608
#define IND_OFF  8388609
#define NE_OFF   8519681
#define NCS_OFF  8552449
#define NEA_OFF  8552961

// ---------------- ws layout (floats) ----------------
#define ET_OFF    0        // E^T : K x DIM  (code rows contiguous)
#define C_OFF     32768    // np-order sum(E*E, axis=0) : K
#define CNT_OFF   33280    // histogram : K           (zeroed each call)
#define ESUM_OFF  33792    // segment sum : K x DIM   (zeroed each call)
#define DSUM_OFF  66560    // diff accumulator : 1    (zeroed each call)

// ============ prep: transpose embed -> E^T, C_j = np.sum(E*E, axis=0) ====
// numpy axis-0 reduce over [64][512]: out[j] = ((E0j^2 + E1j^2) + E2j^2) + ...
// sequential over d, each square rounded fp32, plain adds (NO fma).
__global__ __launch_bounds__(256) void vq_prep(const float* __restrict__ embed,
                                               float* __restrict__ ws) {
    #pragma clang fp contract(off)
    int j = blockIdx.x * 256 + threadIdx.x;   // code index, 0..511
    float c = 0.0f;
    for (int d = 0; d < DIM; ++d) {
        float v = embed[d * K + j];           // coalesced across j
        ws[ET_OFF + j * DIM + d] = v;
        float t = v * v;
        c = c + t;
    }
    ws[C_OFF + j] = c;
}

// ============ main: np-fp32-replica argmin + quantize + diff + stats =====
__global__ __launch_bounds__(256, 2) void vq_assign(
    const float* __restrict__ x,
    const float* __restrict__ ET,      // ws + ET_OFF
    const float* __restrict__ C,       // ws + C_OFF
    float* __restrict__ counts,
    float* __restrict__ esum,
    float* __restrict__ dsum,
    float* __restrict__ out)
{
    #pragma clang fp contract(off)
    int v = blockIdx.x * 256 + threadIdx.x;
    const float* fx = x + (size_t)v * DIM;

    float f[DIM];
    #pragma unroll
    for (int k = 0; k < DIM / 4; ++k) {
        float4 t = ((const float4*)fx)[k];
        f[4*k+0] = t.x; f[4*k+1] = t.y; f[4*k+2] = t.z; f[4*k+3] = t.w;
    }

    // A = np.sum(f*f, axis=1): numpy pairwise, n=64 -> 8 accumulators over
    // strides of 8, then ((r0+r1)+(r2+r3))+((r4+r5)+(r6+r7)). Plain mul+add.
    float r[8];
    #pragma unroll
    for (int k = 0; k < 8; ++k) r[k] = f[k] * f[k];
    #pragma unroll
    for (int b = 1; b < 8; ++b) {
        #pragma unroll
        for (int k = 0; k < 8; ++k) {
            float t = f[8*b + k] * f[8*b + k];
            r[k] = r[k] + t;
        }
    }
    float A = ((r[0] + r[1]) + (r[2] + r[3])) + ((r[4] + r[5]) + (r[6] + r[7]));

    // dist_j = fl(fl(A - fl(2*M_j)) + C_j), M_j = sequential-fma dot (BLAS
    // sgemm microkernel order: one accumulator, k ascending).
    // argmin with strict < ascending j == numpy first-min tie-break.
    float bestd = 3.0e38f;
    int   besti = 0;
    #pragma unroll 4
    for (int j = 0; j < K; ++j) {
        const float* e = ET + j * DIM;   // j wave-uniform -> scalar loads
        float m = 0.0f;
        #pragma unroll
        for (int d = 0; d < DIM; ++d) m = __builtin_fmaf(f[d], e[d], m);
        float t1 = 2.0f * m;             // exact (x2)
        float t2 = A - t1;               // rounded at ulp(~64)
        float dist = t2 + C[j];          // rounded
        if (dist < bestd) { bestd = dist; besti = j; }
    }

    // outputs: index (as float), quantize row, diff partial
    out[IND_OFF + v] = (float)besti;

    const float* q = ET + (size_t)besti * DIM;   // divergent gather, cache-hot
    float dl = 0.0f;
    #pragma unroll
    for (int k = 0; k < DIM / 4; ++k) {
        float4 t = ((const float4*)q)[k];
        float r0 = t.x - f[4*k+0];
        float r1 = t.y - f[4*k+1];
        float r2 = t.z - f[4*k+2];
        float r3 = t.w - f[4*k+3];
        dl = __builtin_fmaf(r0, r0, dl); dl = __builtin_fmaf(r1, r1, dl);
        dl = __builtin_fmaf(r2, r2, dl); dl = __builtin_fmaf(r3, r3, dl);
        ((float4*)(out + Q_OFF + (size_t)v * DIM))[k] = t;
    }

    // stats: histogram + segment sum (global fp32 atomics; 2% thresholds)
    atomicAdd(&counts[besti], 1.0f);
    #pragma unroll
    for (int d = 0; d < DIM; ++d) atomicAdd(&esum[besti * DIM + d], f[d]);

    // diff: wave reduce then one atomic per wave
    #pragma unroll
    for (int off = 32; off > 0; off >>= 1) dl += __shfl_down(dl, off);
    if ((threadIdx.x & 63) == 0) atomicAdd(dsum, dl);
}

// ============ finalize: EMA updates + normalized codebook + diff ==========
__global__ __launch_bounds__(512) void vq_finalize(
    const float* __restrict__ cluster_size,
    const float* __restrict__ embed_avg,
    const float* __restrict__ ws,
    float* __restrict__ out)
{
    __shared__ float wsum[8];
    __shared__ float n_sh;
    int j = threadIdx.x;  // 512 threads, one per code

    float ncs = DECAYF * cluster_size[j] + OMDF * ws[CNT_OFF + j];
    out[NCS_OFF + j] = ncs;

    float s = ncs;
    #pragma unroll
    for (int off = 32; off > 0; off >>= 1) s += __shfl_down(s, off);
    if ((j & 63) == 0) wsum[j >> 6] = s;
    __syncthreads();
    if (j == 0) {
        float n = 0.f;
        #pragma unroll
        for (int w = 0; w < 8; ++w) n += wsum[w];
        n_sh = n;
        out[DIFF_OFF] = ws[DSUM_OFF] * (1.0f / 8388608.0f);  // 2^23: exact
    }
    __syncthreads();
    float n   = n_sh;
    float csz = (ncs + EPSF) / (n + (float)K * EPSF) * n;

    #pragma unroll 4
    for (int d = 0; d < DIM; ++d) {
        float ea = DECAYF * embed_avg[d * K + j] + OMDF * ws[ESUM_OFF + j * DIM + d];
        out[NEA_OFF + d * K + j] = ea;        // coalesced over j
        out[NE_OFF  + d * K + j] = ea / csz;
    }
}

// ============ launch ============
extern "C" void kernel_launch(void* const* d_in, const int* in_sizes, int n_in,
                              void* d_out, int out_size, void* d_ws, size_t ws_size,
                              hipStream_t stream) {
    const float* x            = (const float*)d_in[0];
    const float* embed        = (const float*)d_in[1];
    const float* cluster_size = (const float*)d_in[2];
    const float* embed_avg    = (const float*)d_in[3];
    float* out = (float*)d_out;
    float* ws  = (float*)d_ws;

    // zero the accumulator region (counts + esum + diff) — ws is poisoned 0xAA
    hipMemsetAsync(ws + CNT_OFF, 0, (DSUM_OFF - CNT_OFF + 1) * sizeof(float), stream);

    vq_prep<<<K / 256, 256, 0, stream>>>(embed, ws);
    vq_assign<<<NVEC / 256, 256, 0, stream>>>(
        x, ws + ET_OFF, ws + C_OFF, ws + CNT_OFF, ws + ESUM_OFF, ws + DSUM_OFF, out);
    vq_finalize<<<1, K, 0, stream>>>(cluster_size, embed_avg, ws, out);
}